// Round 2
// baseline (2851.452 us; speedup 1.0000x reference)
//
#include <hip/hip_runtime.h>

// Problem constants
#define Bq 1024
#define Tq 512
#define Fq 64   // input features
#define Hq 128  // hidden
#define Gq 512  // 4*H gates

typedef _Float16 f16;
typedef f16 f16x2 __attribute__((ext_vector_type(2)));

__device__ __forceinline__ float fdot2f(f16x2 a, f16x2 b, float c) {
#if __has_builtin(__builtin_amdgcn_fdot2)
    return __builtin_amdgcn_fdot2(a, b, c, false);
#else
    return c + (float)a.x * (float)b.x + (float)a.y * (float)b.y;
#endif
}

__device__ __forceinline__ f16x2 pack2(float a, float b) {
    f16x2 r; r.x = (f16)a; r.y = (f16)b; return r;
}

__device__ __forceinline__ float sigmoidf_(float x) {
    return 1.f / (1.f + __expf(-x));
}
__device__ __forceinline__ float tanhf_(float x) {
    return 1.f - 2.f / (__expf(2.f * x) + 1.f);
}

union F4H { float4 f4; f16x2 h2[4]; };

// Thread layout (512 threads, 2 batch rows per block):
//   kh = tid & 1       : which K-half of the dot this thread owns
//   g0 = tid >> 1      : first owned gate row (second is g0+256)
// Weights: 2 gate rows x half-K = 96 f16x2 VGPRs (fits under 128, no spill).
// K-half partials combined with one shfl_xor(lane^1).
__global__ __launch_bounds__(512, 4) void lstm_ae_kernel(
    const float* __restrict__ ts,
    const float* __restrict__ Wih_e, const float* __restrict__ Whh_e,
    const float* __restrict__ bih_e, const float* __restrict__ bhh_e,
    const float* __restrict__ Wih_d, const float* __restrict__ Whh_d,
    const float* __restrict__ bih_d, const float* __restrict__ bhh_d,
    const float* __restrict__ Wout, const float* __restrict__ bout,
    float* __restrict__ out)
{
    const int tid = threadIdx.x;
    const int bid = blockIdx.x;
    const int kh = tid & 1;
    const int g0 = tid >> 1;       // 0..255 ; owns gates g0 and g0+256
    const int row0 = bid * 2;

    __shared__ alignas(16) f16x2 x_lds[2][Fq / 2];       // 256 B
    __shared__ alignas(16) f16x2 h_lds[2][Hq / 2];       // 512 B
    __shared__ alignas(16) float gbuf[2][Gq];            // 4 KB
    __shared__ alignas(16) f16x2 wout_lds[Hq / 2][Fq];   // [p][f], 16 KB

    // w[0:16)   = Wih row g0, k-half kh      (16 f16x2 = 32 f16)
    // w[16:48)  = Whh row g0, k-half kh      (32 f16x2 = 64 f16)
    // w[48:64)  = Wih row g0+256, k-half kh
    // w[64:96)  = Whh row g0+256, k-half kh
    f16x2 w[96];
    float bias0, bias1;

    auto load_weights = [&](const float* __restrict__ Wih,
                            const float* __restrict__ Whh,
                            const float* __restrict__ bih,
                            const float* __restrict__ bhh) {
        const float* p0 = Wih + (size_t)g0 * Fq + kh * 32;
        const float* p1 = Wih + (size_t)(g0 + 256) * Fq + kh * 32;
#pragma unroll
        for (int k = 0; k < 16; ++k) {
            float2 a = *(const float2*)(p0 + 2 * k);
            float2 b = *(const float2*)(p1 + 2 * k);
            w[k]      = pack2(a.x, a.y);
            w[48 + k] = pack2(b.x, b.y);
        }
        const float* q0 = Whh + (size_t)g0 * Hq + kh * 64;
        const float* q1 = Whh + (size_t)(g0 + 256) * Hq + kh * 64;
#pragma unroll
        for (int k = 0; k < 32; ++k) {
            float2 a = *(const float2*)(q0 + 2 * k);
            float2 b = *(const float2*)(q1 + 2 * k);
            w[16 + k] = pack2(a.x, a.y);
            w[64 + k] = pack2(b.x, b.y);
        }
        bias0 = bih[g0] + bhh[g0];
        bias1 = bih[g0 + 256] + bhh[g0 + 256];
    };

    // gates for BOTH batch rows fused: 4 independent accumulator chains
    auto gates = [&]() {
        float a00 = 0.f, a01 = 0.f, a10 = 0.f, a11 = 0.f; // a[row][gate]
        const float4* xp0 = (const float4*)(&x_lds[0][kh * 16]);
        const float4* xp1 = (const float4*)(&x_lds[1][kh * 16]);
#pragma unroll
        for (int k4 = 0; k4 < 4; ++k4) {
            F4H u0, u1; u0.f4 = xp0[k4]; u1.f4 = xp1[k4];
#pragma unroll
            for (int i = 0; i < 4; ++i) {
                f16x2 wa = w[k4 * 4 + i];
                f16x2 wb = w[48 + k4 * 4 + i];
                a00 = fdot2f(wa, u0.h2[i], a00);
                a10 = fdot2f(wa, u1.h2[i], a10);
                a01 = fdot2f(wb, u0.h2[i], a01);
                a11 = fdot2f(wb, u1.h2[i], a11);
            }
        }
        const float4* hp0 = (const float4*)(&h_lds[0][kh * 32]);
        const float4* hp1 = (const float4*)(&h_lds[1][kh * 32]);
#pragma unroll
        for (int k4 = 0; k4 < 8; ++k4) {
            F4H u0, u1; u0.f4 = hp0[k4]; u1.f4 = hp1[k4];
#pragma unroll
            for (int i = 0; i < 4; ++i) {
                f16x2 wa = w[16 + k4 * 4 + i];
                f16x2 wb = w[64 + k4 * 4 + i];
                a00 = fdot2f(wa, u0.h2[i], a00);
                a10 = fdot2f(wa, u1.h2[i], a10);
                a01 = fdot2f(wb, u0.h2[i], a01);
                a11 = fdot2f(wb, u1.h2[i], a11);
            }
        }
        // combine k-halves (partner lane = lane^1 holds the other half)
        a00 += __shfl_xor(a00, 1, 64);
        a01 += __shfl_xor(a01, 1, 64);
        a10 += __shfl_xor(a10, 1, 64);
        a11 += __shfl_xor(a11, 1, 64);
        if (kh == 0) {
            gbuf[0][g0]       = a00 + bias0;
            gbuf[0][g0 + 256] = a01 + bias1;
            gbuf[1][g0]       = a10 + bias0;
            gbuf[1][g0 + 256] = a11 + bias1;
        }
    };

    // LSTM pointwise update; thread tid<256 owns one (row, j) unit
    const int urow = (tid >> 7) & 1;
    const int uj = tid & 127;
    float c_reg = 0.f;

    auto update_hc = [&]() {
        float gi = gbuf[urow][uj];
        float gf = gbuf[urow][uj + 128];
        float gg = gbuf[urow][uj + 256];
        float go = gbuf[urow][uj + 384];
        float i_ = sigmoidf_(gi);
        float f_ = sigmoidf_(gf);
        float g_ = tanhf_(gg);
        float o_ = sigmoidf_(go);
        c_reg = f_ * c_reg + i_ * g_;
        float h = o_ * tanhf_(c_reg);
        ((f16*)&h_lds[urow][0])[uj] = (f16)h;
    };

    // ---- init: zero h, stage W_out into LDS, enc weights, x(0) ----
    if (tid < 128) {
        int row = tid >> 6, p = tid & 63;
        f16x2 z; z.x = (f16)0.f; z.y = (f16)0.f;
        h_lds[row][p] = z;
    }
#pragma unroll
    for (int i = 0; i < 8; ++i) {
        int idx = tid * 8 + i;        // 0..4095
        int p = idx >> 6, f = idx & 63;
        wout_lds[p][f] = pack2(Wout[(size_t)f * Hq + 2 * p],
                               Wout[(size_t)f * Hq + 2 * p + 1]);
    }
    load_weights(Wih_e, Whh_e, bih_e, bhh_e);

    if (tid < 64) {
        int row = tid >> 5, p = tid & 31;
        float2 x0 = *(const float2*)(ts + (size_t)(row0 + row) * Tq * Fq + 2 * p);
        x_lds[row][p] = pack2(x0.x, x0.y);
    }
    __syncthreads();

    // ---------------- encoder: 512 steps ----------------
    for (int t = 0; t < Tq; ++t) {
        float2 xn;
        if (tid < 64) {  // prefetch x(t+1)
            int row = tid >> 5, p = tid & 31;
            int tn = (t + 1 < Tq) ? (t + 1) : t;
            xn = *(const float2*)(ts + (size_t)(row0 + row) * Tq * Fq +
                                  (size_t)tn * Fq + 2 * p);
        }
        gates();
        __syncthreads();
        if (tid < 256) update_hc();
        if (tid < 64) {
            int row = tid >> 5, p = tid & 31;
            x_lds[row][p] = pack2(xn.x, xn.y);
        }
        __syncthreads();
    }

    // write c_enc
    if (tid < 256) out[(size_t)(row0 + urow) * Hq + uj] = c_reg;

    // ---------------- switch to decoder ----------------
    load_weights(Wih_d, Whh_d, bih_d, bhh_d);
    float bo = 0.f;
    float err = 0.f;
    float tsv = 0.f;
    if (tid < 128) {
        int row = tid >> 6, f = tid & 63;
        bo = bout[f];
        tsv = ts[(size_t)(row0 + row) * Tq * Fq + (size_t)(Tq - 1) * Fq + f];
    }
    __syncthreads();

    // ---------------- decoder: 512 steps ----------------
    for (int k = 0; k < Tq; ++k) {
        if (tid < 128) {  // hidden2output projection
            int row = tid >> 6, f = tid & 63;
            float a = bo;
            const f16x2* hp = &h_lds[row][0];
#pragma unroll
            for (int p = 0; p < Hq / 2; ++p)
                a = fdot2f(wout_lds[p][f], hp[p], a);
            if (k == 0)
                out[(size_t)Bq * Hq + Bq + (size_t)(row0 + row) * Fq + f] = a;
            err += fabsf(a * a - tsv * tsv);
            int kn = (k + 1 < Tq) ? (k + 1) : k;
            tsv = ts[(size_t)(row0 + row) * Tq * Fq +
                     (size_t)(Tq - 1 - kn) * Fq + f];
            ((f16*)&x_lds[row][0])[f] = (f16)a;
        }
        __syncthreads();
        gates();
        __syncthreads();
        if (tid < 256) update_hc();
        __syncthreads();
    }

    // rec_err: reduce 64 lanes per row (wave 0 = row 0, wave 1 = row 1)
    if (tid < 128) {
        float e = err;
#pragma unroll
        for (int o = 32; o > 0; o >>= 1) e += __shfl_xor(e, o, 64);
        if ((tid & 63) == 0) {
            int row = tid >> 6;
            out[(size_t)Bq * Hq + (row0 + row)] = e;
        }
    }
}

extern "C" void kernel_launch(void* const* d_in, const int* in_sizes, int n_in,
                              void* d_out, int out_size, void* d_ws, size_t ws_size,
                              hipStream_t stream) {
    const float* ts    = (const float*)d_in[0];
    const float* Wih_e = (const float*)d_in[1];
    const float* Whh_e = (const float*)d_in[2];
    const float* bih_e = (const float*)d_in[3];
    const float* bhh_e = (const float*)d_in[4];
    const float* Wih_d = (const float*)d_in[5];
    const float* Whh_d = (const float*)d_in[6];
    const float* bih_d = (const float*)d_in[7];
    const float* bhh_d = (const float*)d_in[8];
    const float* Wout  = (const float*)d_in[9];
    const float* bout  = (const float*)d_in[10];
    float* out = (float*)d_out;

    dim3 grid(Bq / 2);   // 512 blocks, 2 batch rows each
    dim3 block(512);
    hipLaunchKernelGGL(lstm_ae_kernel, grid, block, 0, stream,
                       ts, Wih_e, Whh_e, bih_e, bhh_e,
                       Wih_d, Whh_d, bih_d, bhh_d, Wout, bout, out);
}